// Round 1
// baseline (175.107 us; speedup 1.0000x reference)
//
#include <hip/hip_runtime.h>

// MultiGaussSpatialConv: B=1, N=M=8192, D=3, C=16, fp32.
// out[n,c] = sum_i w_i * (sum_m e_i(n,m) yfea[m,c]) / (sum_m e_i(n,m))
// e_i = exp(-d2 / (2 sigma_i^2)), sigma = {0.05, 0.1, 0.2}, w = {0.3, 0.3, 0.4}
// 1/(2 sigma^2) = {200, 50, 12.5} -> e_200 = e_12.5^16, e_50 = e_12.5^4 (1 exp/pair).

static constexpr int Nn = 8192;
static constexpr int Mm = 8192;
static constexpr int Cc = 16;
static constexpr int TM = 256;   // m-tile staged in LDS
static constexpr int NF = 52;    // 48 numerator + 3 denominator + 1 pad fields

// ---------------- partial kernel: one thread per n, one m-chunk per blockIdx.y
__global__ __launch_bounds__(256) void mgsc_partial(
    const float* __restrict__ x, const float* __restrict__ y,
    const float* __restrict__ yf, float* __restrict__ ws, int mc)
{
    __shared__ float yS[TM * 3];
    __shared__ float yfS[TM * 16];

    const int tid   = threadIdx.x;
    const int n     = blockIdx.x * 256 + tid;
    const int chunk = blockIdx.y;
    const int m0    = chunk * mc;

    const float xx = x[3 * n + 0];
    const float xy = x[3 * n + 1];
    const float xz = x[3 * n + 2];

    float acc0[16], acc1[16], acc2[16];
#pragma unroll
    for (int c = 0; c < 16; ++c) { acc0[c] = 0.f; acc1[c] = 0.f; acc2[c] = 0.f; }
    float den0 = 0.f, den1 = 0.f, den2 = 0.f;

    for (int mt = m0; mt < m0 + mc; mt += TM) {
        // stage y tile: 256*3 floats = 192 float4 (mt multiple of 256 -> 16B aligned)
        const float4* ysrc = reinterpret_cast<const float4*>(y + (size_t)mt * 3);
        if (tid < TM * 3 / 4) reinterpret_cast<float4*>(yS)[tid] = ysrc[tid];
        // stage y_fea tile: 256*16 floats = 1024 float4
        const float4* fsrc = reinterpret_cast<const float4*>(yf + (size_t)mt * 16);
        float4* fdst = reinterpret_cast<float4*>(yfS);
#pragma unroll
        for (int k = 0; k < 4; ++k) fdst[tid + 256 * k] = fsrc[tid + 256 * k];
        __syncthreads();

        for (int mm = 0; mm < TM; ++mm) {
            // wave-uniform LDS index -> broadcast, conflict-free
            const float dx = xx - yS[3 * mm + 0];
            const float dy = xy - yS[3 * mm + 1];
            const float dz = xz - yS[3 * mm + 2];
            const float d2 = dx * dx + dy * dy + dz * dz;   // >= 0 exactly
            const float e2 = __expf(-12.5f * d2);           // sigma = 0.2
            const float t  = e2 * e2;
            const float e1 = t * t;                          // sigma = 0.1  (e2^4)
            const float u  = e1 * e1;
            const float e0 = u * u;                          // sigma = 0.05 (e2^16)
            den0 += e0; den1 += e1; den2 += e2;
            const float4* fr = reinterpret_cast<const float4*>(yfS + mm * 16);
#pragma unroll
            for (int k = 0; k < 4; ++k) {
                const float4 f = fr[k];
                acc0[4 * k + 0] += e0 * f.x; acc0[4 * k + 1] += e0 * f.y;
                acc0[4 * k + 2] += e0 * f.z; acc0[4 * k + 3] += e0 * f.w;
                acc1[4 * k + 0] += e1 * f.x; acc1[4 * k + 1] += e1 * f.y;
                acc1[4 * k + 2] += e1 * f.z; acc1[4 * k + 3] += e1 * f.w;
                acc2[4 * k + 0] += e2 * f.x; acc2[4 * k + 1] += e2 * f.y;
                acc2[4 * k + 2] += e2 * f.z; acc2[4 * k + 3] += e2 * f.w;
            }
        }
        __syncthreads();
    }

    // SoA partial layout ws[chunk][field][N]: coalesced 4B stores across n
    float* wb = ws + (size_t)chunk * NF * Nn;
#pragma unroll
    for (int c = 0; c < 16; ++c) {
        wb[(0 * 16 + c) * Nn + n] = acc0[c];
        wb[(1 * 16 + c) * Nn + n] = acc1[c];
        wb[(2 * 16 + c) * Nn + n] = acc2[c];
    }
    wb[48 * Nn + n] = den0;
    wb[49 * Nn + n] = den1;
    wb[50 * Nn + n] = den2;
}

// ---------------- reduce kernel: one thread per (n, c)
__global__ __launch_bounds__(256) void mgsc_reduce(
    const float* __restrict__ ws, float* __restrict__ out, int nchunks)
{
    const int t = blockIdx.x * 256 + threadIdx.x;
    const int n = t & (Nn - 1);
    const int c = t >> 13;   // N = 2^13
    float s0 = 0.f, s1 = 0.f, s2 = 0.f, d0 = 0.f, d1 = 0.f, d2 = 0.f;
    for (int k = 0; k < nchunks; ++k) {
        const float* wb = ws + (size_t)k * NF * Nn;
        s0 += wb[(0 * 16 + c) * Nn + n];
        s1 += wb[(1 * 16 + c) * Nn + n];
        s2 += wb[(2 * 16 + c) * Nn + n];
        d0 += wb[48 * Nn + n];
        d1 += wb[49 * Nn + n];
        d2 += wb[50 * Nn + n];
    }
    out[(size_t)n * Cc + c] = 0.3f * s0 / d0 + 0.3f * s1 / d1 + 0.4f * s2 / d2;
}

// ---------------- fused fallback (only if workspace is too small for 1 chunk)
__global__ __launch_bounds__(256) void mgsc_fused(
    const float* __restrict__ x, const float* __restrict__ y,
    const float* __restrict__ yf, float* __restrict__ out)
{
    __shared__ float yS[TM * 3];
    __shared__ float yfS[TM * 16];

    const int tid = threadIdx.x;
    const int n   = blockIdx.x * 256 + tid;

    const float xx = x[3 * n + 0];
    const float xy = x[3 * n + 1];
    const float xz = x[3 * n + 2];

    float acc0[16], acc1[16], acc2[16];
#pragma unroll
    for (int c = 0; c < 16; ++c) { acc0[c] = 0.f; acc1[c] = 0.f; acc2[c] = 0.f; }
    float den0 = 0.f, den1 = 0.f, den2 = 0.f;

    for (int mt = 0; mt < Mm; mt += TM) {
        const float4* ysrc = reinterpret_cast<const float4*>(y + (size_t)mt * 3);
        if (tid < TM * 3 / 4) reinterpret_cast<float4*>(yS)[tid] = ysrc[tid];
        const float4* fsrc = reinterpret_cast<const float4*>(yf + (size_t)mt * 16);
        float4* fdst = reinterpret_cast<float4*>(yfS);
#pragma unroll
        for (int k = 0; k < 4; ++k) fdst[tid + 256 * k] = fsrc[tid + 256 * k];
        __syncthreads();

        for (int mm = 0; mm < TM; ++mm) {
            const float dx = xx - yS[3 * mm + 0];
            const float dy = xy - yS[3 * mm + 1];
            const float dz = xz - yS[3 * mm + 2];
            const float d2 = dx * dx + dy * dy + dz * dz;
            const float e2 = __expf(-12.5f * d2);
            const float t  = e2 * e2;
            const float e1 = t * t;
            const float u  = e1 * e1;
            const float e0 = u * u;
            den0 += e0; den1 += e1; den2 += e2;
            const float4* fr = reinterpret_cast<const float4*>(yfS + mm * 16);
#pragma unroll
            for (int k = 0; k < 4; ++k) {
                const float4 f = fr[k];
                acc0[4 * k + 0] += e0 * f.x; acc0[4 * k + 1] += e0 * f.y;
                acc0[4 * k + 2] += e0 * f.z; acc0[4 * k + 3] += e0 * f.w;
                acc1[4 * k + 0] += e1 * f.x; acc1[4 * k + 1] += e1 * f.y;
                acc1[4 * k + 2] += e1 * f.z; acc1[4 * k + 3] += e1 * f.w;
                acc2[4 * k + 0] += e2 * f.x; acc2[4 * k + 1] += e2 * f.y;
                acc2[4 * k + 2] += e2 * f.z; acc2[4 * k + 3] += e2 * f.w;
            }
        }
        __syncthreads();
    }

    const float r0 = 0.3f / den0, r1 = 0.3f / den1, r2 = 0.4f / den2;
#pragma unroll
    for (int c = 0; c < 16; ++c)
        out[(size_t)n * Cc + c] = acc0[c] * r0 + acc1[c] * r1 + acc2[c] * r2;
}

extern "C" void kernel_launch(void* const* d_in, const int* in_sizes, int n_in,
                              void* d_out, int out_size, void* d_ws, size_t ws_size,
                              hipStream_t stream) {
    const float* x  = (const float*)d_in[0];
    const float* y  = (const float*)d_in[1];
    const float* yf = (const float*)d_in[2];
    float* out = (float*)d_out;
    float* ws  = (float*)d_ws;

    const size_t chunk_bytes = (size_t)NF * Nn * sizeof(float);  // 1.7 MB per chunk
    if (ws_size < chunk_bytes) {
        // workspace too small for even one partial chunk: fused (slow) path
        mgsc_fused<<<Nn / 256, 256, 0, stream>>>(x, y, yf, out);
        return;
    }
    int nchunks = 32;
    while (nchunks > 1 && (size_t)nchunks * chunk_bytes > ws_size) nchunks >>= 1;
    const int mc = Mm / nchunks;

    dim3 grid(Nn / 256, nchunks);
    mgsc_partial<<<grid, 256, 0, stream>>>(x, y, yf, ws, mc);
    mgsc_reduce<<<(Nn * Cc) / 256, 256, 0, stream>>>(ws, out, nchunks);
}

// Round 2
// 127.604 us; speedup vs baseline: 1.3723x; 1.3723x over previous
//
#include <hip/hip_runtime.h>

// MultiGaussSpatialConv: B=1, N=M=8192, D=3, C=16, fp32.
// out[n,c] = sum_i w_i * (sum_m e_i(n,m) yf[m,c]) / (sum_m e_i(n,m))
// e_i = exp(-d2/(2 s_i^2)); 1/(2 s^2) = {200, 50, 12.5} -> e0=e2^16, e1=e2^4.
// R2: contraction moved to MFMA via split-bf16 (e=eh+el, yf=fh+fl; 3 products,
// fp32 accumulate). Dens via MFMA against a ones-column B fragment.

static constexpr int Nn = 8192;
static constexpr int Mm = 8192;
static constexpr int Cc = 16;
static constexpr int NF = 52;    // 48 num + 3 den + 1 pad fields per chunk

typedef __attribute__((ext_vector_type(8))) short short8;
typedef __attribute__((ext_vector_type(4))) float float4v;

#define MFMA_BF16 __builtin_amdgcn_mfma_f32_16x16x32_bf16

// ---------------- prep: q[m]=(yx,yy,yz,|y|^2); yf -> hi/lo bf16 in B-frag layout
// frag index for (m,c): (m>>5)*512 + (((m&31)>>3)*16 + c)*8 + (m&7)
__global__ __launch_bounds__(256) void mgsc_prep(
    const float* __restrict__ y, const float* __restrict__ yf,
    float4* __restrict__ q, unsigned short* __restrict__ yfh,
    unsigned short* __restrict__ yfl)
{
    const int t = blockIdx.x * 256 + threadIdx.x;   // 0 .. Mm*Cc-1
    const int m = t >> 4, c = t & 15;
    const float v = yf[t];
    const unsigned int ub = __float_as_uint(v);
    const unsigned int hb = ub & 0xffff0000u;
    const float lo = v - __uint_as_float(hb);
    const int idx = ((m >> 5) << 9) + ((((m & 31) >> 3) << 4) + c) * 8 + (m & 7);
    yfh[idx] = (unsigned short)(ub >> 16);
    yfl[idx] = (unsigned short)(__float_as_uint(lo) >> 16);
    if (t < Mm) {
        const float ax = y[3 * t], ay = y[3 * t + 1], az = y[3 * t + 2];
        q[t] = make_float4(ax, ay, az, ax * ax + ay * ay + az * az);
    }
}

// ---------------- main: one wave per 16-n tile, K-step = 32 m, no LDS
__global__ __launch_bounds__(256) void mgsc_mfma(
    const float* __restrict__ x, const float4* __restrict__ q,
    const unsigned short* __restrict__ yfh, const unsigned short* __restrict__ yfl,
    float* __restrict__ ws, int mc)
{
    const int tid  = threadIdx.x;
    const int wave = tid >> 6, lane = tid & 63;
    const int g    = lane >> 4, c = lane & 15;
    const int ntile = blockIdx.x * 64 + wave * 16;
    const int nrow  = ntile + c;                      // A row for this lane

    const float xx = x[3 * nrow], xy = x[3 * nrow + 1], xz = x[3 * nrow + 2];
    const float x2 = xx * xx + xy * xy + xz * xz;

    float4v acc0 = {0.f, 0.f, 0.f, 0.f}, acc1 = acc0, acc2 = acc0;
    float4v dac0 = acc0, dac1 = acc0, dac2 = acc0;

    short8 bone;                                      // B ones-column (c==0)
#pragma unroll
    for (int j = 0; j < 8; ++j) bone[j] = (c == 0) ? (short)0x3F80 : (short)0;

    const int kt0 = blockIdx.y * (mc >> 5);
    const int kte = kt0 + (mc >> 5);

    for (int kt = kt0; kt < kte; ++kt) {
        const float4* qp = q + (kt << 5) + (g << 3);
        short8 eh0, eh1, eh2, el0, el1, el2;
#pragma unroll
        for (int j = 0; j < 8; ++j) {
            const float4 Q = qp[j];
            const float p  = __fmaf_rn(xz, Q.z, __fmaf_rn(xy, Q.y, xx * Q.x));
            float d2 = __fmaf_rn(-2.f, p, x2 + Q.w);
            d2 = fmaxf(d2, 0.f);
            const float e2 = __expf(-12.5f * d2);
            const float t2 = e2 * e2;
            const float e1 = t2 * t2;                 // e2^4  (sigma 0.1)
            const float u2 = e1 * e1;
            const float e0 = u2 * u2;                 // e2^16 (sigma 0.05)
            const unsigned int b0 = __float_as_uint(e0);
            eh0[j] = (short)(b0 >> 16);
            el0[j] = (short)(__float_as_uint(e0 - __uint_as_float(b0 & 0xffff0000u)) >> 16);
            const unsigned int b1 = __float_as_uint(e1);
            eh1[j] = (short)(b1 >> 16);
            el1[j] = (short)(__float_as_uint(e1 - __uint_as_float(b1 & 0xffff0000u)) >> 16);
            const unsigned int b2 = __float_as_uint(e2);
            eh2[j] = (short)(b2 >> 16);
            el2[j] = (short)(__float_as_uint(e2 - __uint_as_float(b2 & 0xffff0000u)) >> 16);
        }
        const short8 Bh = *(const short8*)(yfh + ((size_t)kt << 9) + (lane << 3));
        const short8 Bl = *(const short8*)(yfl + ((size_t)kt << 9) + (lane << 3));

        acc0 = MFMA_BF16(eh0, Bh, acc0, 0, 0, 0);
        acc0 = MFMA_BF16(eh0, Bl, acc0, 0, 0, 0);
        acc0 = MFMA_BF16(el0, Bh, acc0, 0, 0, 0);
        acc1 = MFMA_BF16(eh1, Bh, acc1, 0, 0, 0);
        acc1 = MFMA_BF16(eh1, Bl, acc1, 0, 0, 0);
        acc1 = MFMA_BF16(el1, Bh, acc1, 0, 0, 0);
        acc2 = MFMA_BF16(eh2, Bh, acc2, 0, 0, 0);
        acc2 = MFMA_BF16(eh2, Bl, acc2, 0, 0, 0);
        acc2 = MFMA_BF16(el2, Bh, acc2, 0, 0, 0);
        dac0 = MFMA_BF16(eh0, bone, dac0, 0, 0, 0);
        dac0 = MFMA_BF16(el0, bone, dac0, 0, 0, 0);
        dac1 = MFMA_BF16(eh1, bone, dac1, 0, 0, 0);
        dac1 = MFMA_BF16(el1, bone, dac1, 0, 0, 0);
        dac2 = MFMA_BF16(eh2, bone, dac2, 0, 0, 0);
        dac2 = MFMA_BF16(el2, bone, dac2, 0, 0, 0);
    }

    // epilogue: C/D layout col=lane&15 (=c), row=g*4+reg  [m89-verified]
    float* wb = ws + (size_t)blockIdx.y * NF * Nn;
#pragma unroll
    for (int r = 0; r < 4; ++r) {
        const int nr = ntile + (g << 2) + r;
        wb[(0 * 16 + c) * Nn + nr] = acc0[r];
        wb[(1 * 16 + c) * Nn + nr] = acc1[r];
        wb[(2 * 16 + c) * Nn + nr] = acc2[r];
    }
    if (c == 0) {
#pragma unroll
        for (int r = 0; r < 4; ++r) {
            const int nr = ntile + (g << 2) + r;
            wb[48 * Nn + nr] = dac0[r];
            wb[49 * Nn + nr] = dac1[r];
            wb[50 * Nn + nr] = dac2[r];
        }
    }
}

// ---------------- reduce: one thread per (n, c)
__global__ __launch_bounds__(256) void mgsc_reduce(
    const float* __restrict__ ws, float* __restrict__ out, int nchunks)
{
    const int t = blockIdx.x * 256 + threadIdx.x;
    const int n = t & (Nn - 1);
    const int c = t >> 13;
    float s0 = 0.f, s1 = 0.f, s2 = 0.f, d0 = 0.f, d1 = 0.f, d2 = 0.f;
    for (int k = 0; k < nchunks; ++k) {
        const float* wb = ws + (size_t)k * NF * Nn;
        s0 += wb[(0 * 16 + c) * Nn + n];
        s1 += wb[(1 * 16 + c) * Nn + n];
        s2 += wb[(2 * 16 + c) * Nn + n];
        d0 += wb[48 * Nn + n];
        d1 += wb[49 * Nn + n];
        d2 += wb[50 * Nn + n];
    }
    out[(size_t)n * Cc + c] = 0.3f * s0 / d0 + 0.3f * s1 / d1 + 0.4f * s2 / d2;
}

// ---------------- fused VALU fallback (workspace too small)
__global__ __launch_bounds__(256) void mgsc_fused(
    const float* __restrict__ x, const float* __restrict__ y,
    const float* __restrict__ yf, float* __restrict__ out)
{
    __shared__ float yS[256 * 3];
    __shared__ float yfS[256 * 16];
    const int tid = threadIdx.x;
    const int n   = blockIdx.x * 256 + tid;
    const float xx = x[3 * n], xy = x[3 * n + 1], xz = x[3 * n + 2];
    float a0[16], a1[16], a2[16];
#pragma unroll
    for (int c = 0; c < 16; ++c) { a0[c] = 0.f; a1[c] = 0.f; a2[c] = 0.f; }
    float den0 = 0.f, den1 = 0.f, den2 = 0.f;
    for (int mt = 0; mt < Mm; mt += 256) {
        const float4* ysrc = reinterpret_cast<const float4*>(y + (size_t)mt * 3);
        if (tid < 192) reinterpret_cast<float4*>(yS)[tid] = ysrc[tid];
        const float4* fsrc = reinterpret_cast<const float4*>(yf + (size_t)mt * 16);
#pragma unroll
        for (int k = 0; k < 4; ++k)
            reinterpret_cast<float4*>(yfS)[tid + 256 * k] = fsrc[tid + 256 * k];
        __syncthreads();
        for (int mm = 0; mm < 256; ++mm) {
            const float dx = xx - yS[3 * mm], dy = xy - yS[3 * mm + 1], dz = xz - yS[3 * mm + 2];
            const float d2 = dx * dx + dy * dy + dz * dz;
            const float e2 = __expf(-12.5f * d2);
            const float t = e2 * e2, e1 = t * t, u = e1 * e1, e0 = u * u;
            den0 += e0; den1 += e1; den2 += e2;
            const float4* fr = reinterpret_cast<const float4*>(yfS + mm * 16);
#pragma unroll
            for (int k = 0; k < 4; ++k) {
                const float4 f = fr[k];
                a0[4*k+0] += e0 * f.x; a0[4*k+1] += e0 * f.y; a0[4*k+2] += e0 * f.z; a0[4*k+3] += e0 * f.w;
                a1[4*k+0] += e1 * f.x; a1[4*k+1] += e1 * f.y; a1[4*k+2] += e1 * f.z; a1[4*k+3] += e1 * f.w;
                a2[4*k+0] += e2 * f.x; a2[4*k+1] += e2 * f.y; a2[4*k+2] += e2 * f.z; a2[4*k+3] += e2 * f.w;
            }
        }
        __syncthreads();
    }
    const float r0 = 0.3f / den0, r1 = 0.3f / den1, r2 = 0.4f / den2;
#pragma unroll
    for (int c = 0; c < 16; ++c)
        out[(size_t)n * Cc + c] = a0[c] * r0 + a1[c] * r1 + a2[c] * r2;
}

extern "C" void kernel_launch(void* const* d_in, const int* in_sizes, int n_in,
                              void* d_out, int out_size, void* d_ws, size_t ws_size,
                              hipStream_t stream) {
    const float* x  = (const float*)d_in[0];
    const float* y  = (const float*)d_in[1];
    const float* yf = (const float*)d_in[2];
    float* out = (float*)d_out;

    const size_t fragB = (size_t)Mm * Cc * sizeof(unsigned short);  // 256 KB
    const size_t qB    = (size_t)Mm * sizeof(float4);               // 128 KB
    const size_t chunkB = (size_t)NF * Nn * sizeof(float);          // 1.67 MB

    int nchunks = 16;
    while (nchunks > 1 && (size_t)nchunks * chunkB + qB + 2 * fragB > ws_size)
        nchunks >>= 1;
    if ((size_t)nchunks * chunkB + qB + 2 * fragB > ws_size) {
        mgsc_fused<<<Nn / 256, 256, 0, stream>>>(x, y, yf, out);
        return;
    }

    char* base = (char*)d_ws;
    float* part = (float*)base;
    size_t off = (size_t)nchunks * chunkB;
    float4* q = (float4*)(base + off);              off += qB;
    unsigned short* yfh = (unsigned short*)(base + off);  off += fragB;
    unsigned short* yfl = (unsigned short*)(base + off);

    mgsc_prep<<<(Mm * Cc) / 256, 256, 0, stream>>>(y, yf, q, yfh, yfl);
    const int mc = Mm / nchunks;
    dim3 grid(Nn / 64, nchunks);
    mgsc_mfma<<<grid, 256, 0, stream>>>(x, q, yfh, yfl, part, mc);
    mgsc_reduce<<<(Nn * Cc) / 256, 256, 0, stream>>>(part, out, nchunks);
}